// Round 2
// baseline (1429.894 us; speedup 1.0000x reference)
//
#include <hip/hip_runtime.h>

#define NEG_SLOPE 0.2f

// ---------------------------------------------------------------------------
// CSR build: histogram -> single-block scan -> scatter
// ---------------------------------------------------------------------------
__global__ void hist_kernel(const int* __restrict__ dst, int* __restrict__ deg, int E) {
    for (int i = blockIdx.x * blockDim.x + threadIdx.x; i < E; i += gridDim.x * blockDim.x)
        atomicAdd(&deg[dst[i]], 1);
}

__global__ __launch_bounds__(1024) void scan_kernel(const int* __restrict__ deg,
                                                    int* __restrict__ row_ptr,
                                                    int* __restrict__ cursor, int n) {
    __shared__ int wave_part[16];
    __shared__ int carry_s;
    const int tid = threadIdx.x;
    const int lane = tid & 63;
    const int wid = tid >> 6;
    if (tid == 0) carry_s = 0;
    __syncthreads();
    for (int base = 0; base < n; base += 4096) {
        int idx0 = base + tid * 4;
        int v0 = (idx0 + 0 < n) ? deg[idx0 + 0] : 0;
        int v1 = (idx0 + 1 < n) ? deg[idx0 + 1] : 0;
        int v2 = (idx0 + 2 < n) ? deg[idx0 + 2] : 0;
        int v3 = (idx0 + 3 < n) ? deg[idx0 + 3] : 0;
        int tsum = v0 + v1 + v2 + v3;
        int inc = tsum;
        #pragma unroll
        for (int off = 1; off < 64; off <<= 1) {
            int o = __shfl_up(inc, off, 64);
            if (lane >= off) inc += o;
        }
        if (lane == 63) wave_part[wid] = inc;
        __syncthreads();
        if (tid == 0) {
            int run = 0;
            #pragma unroll
            for (int w = 0; w < 16; ++w) { int t = wave_part[w]; wave_part[w] = run; run += t; }
        }
        __syncthreads();
        int run = inc - tsum + wave_part[wid] + carry_s;
        if (idx0 + 0 < n) { row_ptr[idx0 + 0] = run; cursor[idx0 + 0] = run; } run += v0;
        if (idx0 + 1 < n) { row_ptr[idx0 + 1] = run; cursor[idx0 + 1] = run; } run += v1;
        if (idx0 + 2 < n) { row_ptr[idx0 + 2] = run; cursor[idx0 + 2] = run; } run += v2;
        if (idx0 + 3 < n) { row_ptr[idx0 + 3] = run; cursor[idx0 + 3] = run; } run += v3;
        __syncthreads();
        if (tid == 1023) carry_s += wave_part[15] + inc;  // inc == wave-15 inclusive total
        __syncthreads();
    }
    if (tid == 0) row_ptr[n] = carry_s;
}

__global__ void scatter_kernel(const int* __restrict__ src, const int* __restrict__ dst,
                               int* __restrict__ cursor, int2* __restrict__ csr, int E) {
    for (int i = blockIdx.x * blockDim.x + threadIdx.x; i < E; i += gridDim.x * blockDim.x) {
        int d = dst[i];
        int pos = atomicAdd(&cursor[d], 1);
        csr[pos] = make_int2(src[i], i);
    }
}

// ---------------------------------------------------------------------------
// Dense linear: out[M,256] = A[M,K] @ W[K,256] (+bias, relu) — fp32 vector ALU
// Block: 256 threads, 16 rows/block, thread owns one output column.
// ---------------------------------------------------------------------------
template <int K, bool BIAS_RELU>
__global__ __launch_bounds__(256) void linear_ker(const float* __restrict__ A,
                                                  const float* __restrict__ W,
                                                  const float* __restrict__ bias,
                                                  float* __restrict__ out, int M) {
    constexpr int ROWS = 16;
    constexpr int KV = K / 4;
    __shared__ float4 lds_a[ROWS * KV];
    const int row0 = blockIdx.x * ROWS;
    const int tid = threadIdx.x;

    // stage 16 rows of A into LDS (vectorized, coalesced)
    for (int i = tid; i < ROWS * KV; i += 256) {
        int r = i / KV, kv = i - r * KV;
        int row = row0 + r;
        float4 v = make_float4(0.f, 0.f, 0.f, 0.f);
        if (row < M) v = reinterpret_cast<const float4*>(A + (size_t)row * K)[kv];
        lds_a[i] = v;
    }
    __syncthreads();

    const int c = tid;
    float acc[ROWS];
    #pragma unroll
    for (int r = 0; r < ROWS; ++r) acc[r] = 0.f;

    for (int k0 = 0; k0 < K; k0 += 4) {
        float w0 = W[(k0 + 0) * 256 + c];
        float w1 = W[(k0 + 1) * 256 + c];
        float w2 = W[(k0 + 2) * 256 + c];
        float w3 = W[(k0 + 3) * 256 + c];
        #pragma unroll
        for (int r = 0; r < ROWS; ++r) {
            float4 av = lds_a[r * KV + (k0 >> 2)];
            acc[r] = fmaf(av.x, w0, acc[r]);
            acc[r] = fmaf(av.y, w1, acc[r]);
            acc[r] = fmaf(av.z, w2, acc[r]);
            acc[r] = fmaf(av.w, w3, acc[r]);
        }
    }

    float b = BIAS_RELU ? bias[c] : 0.f;
    #pragma unroll
    for (int r = 0; r < ROWS; ++r) {
        int row = row0 + r;
        if (row < M) {
            float v = acc[r] + b;
            if (BIAS_RELU) v = fmaxf(v, 0.f);
            out[(size_t)row * 256 + c] = v;
        }
    }
}

// ---------------------------------------------------------------------------
// el/er: per-node, per-head dot of h with attn vectors. One wave per node.
// ---------------------------------------------------------------------------
__global__ __launch_bounds__(256) void eler_kernel(const float* __restrict__ h,
                                                   const float* __restrict__ al,
                                                   const float* __restrict__ ar,
                                                   float* __restrict__ el,
                                                   float* __restrict__ er, int N) {
    int wid = threadIdx.x >> 6, lane = threadIdx.x & 63;
    int n = blockIdx.x * 4 + wid;
    if (n >= N) return;
    float4 hv = reinterpret_cast<const float4*>(h + (size_t)n * 256)[lane];
    float4 av = reinterpret_cast<const float4*>(al)[lane];
    float4 rv = reinterpret_cast<const float4*>(ar)[lane];
    float pl = hv.x * av.x + hv.y * av.y + hv.z * av.z + hv.w * av.w;
    float pr = hv.x * rv.x + hv.y * rv.y + hv.z * rv.z + hv.w * rv.w;
    #pragma unroll
    for (int off = 1; off < 16; off <<= 1) {
        pl += __shfl_xor(pl, off, 64);
        pr += __shfl_xor(pr, off, 64);
    }
    if ((lane & 15) == 0) {
        int hh = lane >> 4;
        el[n * 4 + hh] = pl;
        er[n * 4 + hh] = pr;
    }
}

// ---------------------------------------------------------------------------
// per-edge exp(leaky_relu(el[src]+er[dst])) and segment-sum into s[dst]
// (softmax max-shift skipped: mathematically invariant; |e| is O(1))
// ---------------------------------------------------------------------------
__global__ void ex_kernel(const int* __restrict__ src, const int* __restrict__ dst,
                          const float* __restrict__ el, const float* __restrict__ er,
                          float* __restrict__ ex, float* __restrict__ s, int E4) {
    int i = blockIdx.x * blockDim.x + threadIdx.x;
    if (i >= E4) return;
    int e = i >> 2, h = i & 3;
    int sn = src[e], dn = dst[e];
    float v = el[sn * 4 + h] + er[dn * 4 + h];
    v = (v > 0.f) ? v : NEG_SLOPE * v;
    float xv = expf(v);
    ex[i] = xv;
    atomicAdd(&s[dn * 4 + h], xv);
}

// ---------------------------------------------------------------------------
// Aggregation per dst node: out = (sum_e ex_e * h[src_e]) / s + res + bias, relu
// One block (256 threads) per node; thread owns one channel. No atomics.
// ---------------------------------------------------------------------------
__global__ __launch_bounds__(256) void agg_kernel(const int* __restrict__ row_ptr,
                                                  const int2* __restrict__ csr,
                                                  const float* __restrict__ hfeat,
                                                  const float* __restrict__ ex,
                                                  const float* __restrict__ s,
                                                  const float* __restrict__ res,
                                                  const float* __restrict__ bias,
                                                  float* __restrict__ out, int N) {
    int n = blockIdx.x;
    int c = threadIdx.x;
    int hc = c >> 6;
    int start = row_ptr[n], end = row_ptr[n + 1];
    float acc = 0.f;
    for (int p = start; p < end; ++p) {
        int2 se = csr[p];
        float w = ex[se.y * 4 + hc];
        acc = fmaf(w, hfeat[(size_t)se.x * 256 + c], acc);
    }
    float sinv = 1.f / s[n * 4 + hc];
    float v = acc * sinv + res[(size_t)n * 256 + c] + bias[c];
    v = fmaxf(v, 0.f);
    out[(size_t)n * 256 + c] = v;
}

// ---------------------------------------------------------------------------
// Column-wise max pool over nodes (values >= 0 post-ReLU -> int atomicMax ok)
// ---------------------------------------------------------------------------
__global__ void maxpool_kernel(const float* __restrict__ x, float* __restrict__ pooled, int N) {
    int c = threadIdx.x;
    float m = 0.f;
    for (int n = blockIdx.x; n < N; n += gridDim.x)
        m = fmaxf(m, x[(size_t)n * 256 + c]);
    atomicMax(reinterpret_cast<int*>(pooled) + c, __float_as_int(m));
}

// ---------------------------------------------------------------------------
// Final tiny MLP: [1,256] @ [256,128] relu @ [128,2]
// ---------------------------------------------------------------------------
__global__ __launch_bounds__(128) void mlp_kernel(const float* __restrict__ pooled,
                                                  const float* __restrict__ Ws,
                                                  const float* __restrict__ bs,
                                                  const float* __restrict__ Wc,
                                                  const float* __restrict__ bc,
                                                  float* __restrict__ out) {
    __shared__ float p[256];
    __shared__ float hbuf[128];
    int t = threadIdx.x;
    p[t] = pooled[t];
    p[t + 128] = pooled[t + 128];
    __syncthreads();
    float acc = bs[t];
    for (int k = 0; k < 256; ++k) acc = fmaf(p[k], Ws[k * 128 + t], acc);
    hbuf[t] = fmaxf(acc, 0.f);
    __syncthreads();
    if (t < 2) {
        float o = bc[t];
        for (int k = 0; k < 128; ++k) o = fmaf(hbuf[k], Wc[k * 2 + t], o);
        out[t] = o;
    }
}

// ---------------------------------------------------------------------------
extern "C" void kernel_launch(void* const* d_in, const int* in_sizes, int n_in,
                              void* d_out, int out_size, void* d_ws, size_t ws_size,
                              hipStream_t stream) {
    const float* doc   = (const float*)d_in[0];
    const float* wordf = (const float*)d_in[1];
    const int*   src   = (const int*)d_in[2];
    const int*   dst   = (const int*)d_in[3];
    const float* Wd    = (const float*)d_in[4];
    const float* bd    = (const float*)d_in[5];
    const float* Ww    = (const float*)d_in[6];
    const float* bw    = (const float*)d_in[7];
    const float* W1    = (const float*)d_in[8];
    const float* al1   = (const float*)d_in[9];
    const float* ar1   = (const float*)d_in[10];
    const float* b1    = (const float*)d_in[11];
    const float* resW1 = (const float*)d_in[12];
    const float* W2    = (const float*)d_in[13];
    const float* al2   = (const float*)d_in[14];
    const float* ar2   = (const float*)d_in[15];
    const float* b2    = (const float*)d_in[16];
    const float* Wsm   = (const float*)d_in[17];
    const float* bsm   = (const float*)d_in[18];
    const float* Wc    = (const float*)d_in[19];
    const float* bc    = (const float*)d_in[20];

    const int NDOC  = in_sizes[0] / 768;
    const int NWORD = in_sizes[1] / 300;
    const int N     = NDOC + NWORD;
    const int E     = in_sizes[2];

    char* ws = (char*)d_ws;
    size_t off = 0;
    auto alloc = [&](size_t bytes) -> char* {
        char* p = ws + off;
        off = (off + bytes + 255) & ~(size_t)255;
        return p;
    };
    float* X      = (float*)alloc((size_t)N * 256 * 4);
    float* Hb     = (float*)alloc((size_t)N * 256 * 4);
    float* R      = (float*)alloc((size_t)N * 256 * 4);
    float* EL     = (float*)alloc((size_t)N * 4 * 4);
    float* ER     = (float*)alloc((size_t)N * 4 * 4);
    float* S      = (float*)alloc((size_t)N * 4 * 4);
    float* EX     = (float*)alloc((size_t)E * 4 * 4);
    int*   rowptr = (int*)alloc((size_t)(N + 1) * 4);
    int*   cursor = (int*)alloc((size_t)N * 4);
    int*   deg    = (int*)alloc((size_t)N * 4);
    int2*  csr    = (int2*)alloc((size_t)E * 8);
    float* pooled = (float*)alloc(256 * 4);

    const int eg  = (E + 255) / 256;
    const int e4g = (E * 4 + 255) / 256;

    // --- CSR build (by dst), reused for both layers ---
    hipMemsetAsync(deg, 0, (size_t)N * 4, stream);
    hist_kernel<<<eg, 256, 0, stream>>>(dst, deg, E);
    scan_kernel<<<1, 1024, 0, stream>>>(deg, rowptr, cursor, N);
    scatter_kernel<<<eg, 256, 0, stream>>>(src, dst, cursor, csr, E);

    // --- input linears -> X ---
    linear_ker<768, true><<<(NDOC + 15) / 16, 256, 0, stream>>>(doc, Wd, bd, X, NDOC);
    linear_ker<300, true><<<(NWORD + 15) / 16, 256, 0, stream>>>(wordf, Ww, bw,
                                                                 X + (size_t)NDOC * 256, NWORD);

    // --- GAT layer 1 ---
    linear_ker<256, false><<<(N + 15) / 16, 256, 0, stream>>>(X, resW1, nullptr, R, N);
    linear_ker<256, false><<<(N + 15) / 16, 256, 0, stream>>>(X, W1, nullptr, Hb, N);
    eler_kernel<<<(N + 3) / 4, 256, 0, stream>>>(Hb, al1, ar1, EL, ER, N);
    hipMemsetAsync(S, 0, (size_t)N * 16, stream);
    ex_kernel<<<e4g, 256, 0, stream>>>(src, dst, EL, ER, EX, S, E * 4);
    agg_kernel<<<N, 256, 0, stream>>>(rowptr, csr, Hb, EX, S, R, b1, X, N);

    // --- GAT layer 2 (identity residual = X) ---
    linear_ker<256, false><<<(N + 15) / 16, 256, 0, stream>>>(X, W2, nullptr, Hb, N);
    eler_kernel<<<(N + 3) / 4, 256, 0, stream>>>(Hb, al2, ar2, EL, ER, N);
    hipMemsetAsync(S, 0, (size_t)N * 16, stream);
    ex_kernel<<<e4g, 256, 0, stream>>>(src, dst, EL, ER, EX, S, E * 4);
    agg_kernel<<<N, 256, 0, stream>>>(rowptr, csr, Hb, EX, S, X, b2, R, N);

    // --- max pool + classifier ---
    hipMemsetAsync(pooled, 0, 256 * 4, stream);
    maxpool_kernel<<<256, 256, 0, stream>>>(R, pooled, N);
    mlp_kernel<<<1, 128, 0, stream>>>(pooled, Wsm, bsm, Wc, bc, (float*)d_out);
}

// Round 7
// 858.762 us; speedup vs baseline: 1.6651x; 1.6651x over previous
//
#include <hip/hip_runtime.h>

#define NEG_SLOPE 0.2f

typedef __attribute__((ext_vector_type(8))) short bf16x8;
typedef __attribute__((ext_vector_type(4))) float f32x4;

__device__ __forceinline__ unsigned short f2bf(float x) {
    unsigned u = __float_as_uint(x);
    unsigned r = (u + 0x7fffu + ((u >> 16) & 1u)) >> 16;
    return (unsigned short)r;
}
__device__ __forceinline__ float bf2f(unsigned short b) {
    return __uint_as_float(((unsigned)b) << 16);
}

// ---------------------------------------------------------------------------
// CSR build: histogram -> single-block scan -> scatter
// ---------------------------------------------------------------------------
__global__ void hist_kernel(const int* __restrict__ dst, int* __restrict__ deg, int E) {
    for (int i = blockIdx.x * blockDim.x + threadIdx.x; i < E; i += gridDim.x * blockDim.x)
        atomicAdd(&deg[dst[i]], 1);
}

__global__ __launch_bounds__(1024) void scan_kernel(const int* __restrict__ deg,
                                                    int* __restrict__ row_ptr,
                                                    int* __restrict__ cursor, int n) {
    __shared__ int wave_part[16];
    __shared__ int carry_s;
    const int tid = threadIdx.x;
    const int lane = tid & 63;
    const int wid = tid >> 6;
    if (tid == 0) carry_s = 0;
    __syncthreads();
    for (int base = 0; base < n; base += 4096) {
        int idx0 = base + tid * 4;
        int v0 = (idx0 + 0 < n) ? deg[idx0 + 0] : 0;
        int v1 = (idx0 + 1 < n) ? deg[idx0 + 1] : 0;
        int v2 = (idx0 + 2 < n) ? deg[idx0 + 2] : 0;
        int v3 = (idx0 + 3 < n) ? deg[idx0 + 3] : 0;
        int tsum = v0 + v1 + v2 + v3;
        int inc = tsum;
        #pragma unroll
        for (int off = 1; off < 64; off <<= 1) {
            int o = __shfl_up(inc, off, 64);
            if (lane >= off) inc += o;
        }
        if (lane == 63) wave_part[wid] = inc;
        __syncthreads();
        if (tid == 0) {
            int run = 0;
            #pragma unroll
            for (int w = 0; w < 16; ++w) { int t = wave_part[w]; wave_part[w] = run; run += t; }
        }
        __syncthreads();
        int run = inc - tsum + wave_part[wid] + carry_s;
        if (idx0 + 0 < n) { row_ptr[idx0 + 0] = run; cursor[idx0 + 0] = run; } run += v0;
        if (idx0 + 1 < n) { row_ptr[idx0 + 1] = run; cursor[idx0 + 1] = run; } run += v1;
        if (idx0 + 2 < n) { row_ptr[idx0 + 2] = run; cursor[idx0 + 2] = run; } run += v2;
        if (idx0 + 3 < n) { row_ptr[idx0 + 3] = run; cursor[idx0 + 3] = run; } run += v3;
        __syncthreads();
        if (tid == 1023) carry_s += wave_part[15] + inc;
        __syncthreads();
    }
    if (tid == 0) row_ptr[n] = carry_s;
}

__global__ void scatter_kernel(const int* __restrict__ src, const int* __restrict__ dst,
                               int* __restrict__ cursor, int2* __restrict__ csr, int E) {
    for (int i = blockIdx.x * blockDim.x + threadIdx.x; i < E; i += gridDim.x * blockDim.x) {
        int d = dst[i];
        int pos = atomicAdd(&cursor[d], 1);
        csr[pos] = make_int2(src[i], i);
    }
}

// ---------------------------------------------------------------------------
// W^T build: WT[c][k] = bf16(W[k][c]), k padded to KPAD with zeros. C = 256.
// ---------------------------------------------------------------------------
__global__ void wt_kernel(const float* __restrict__ W, unsigned short* __restrict__ WT,
                          int K, int KPAD) {
    int i = blockIdx.x * 256 + threadIdx.x;
    if (i >= 256 * KPAD) return;
    int c = i / KPAD, k = i - c * KPAD;
    WT[i] = (k < K) ? f2bf(W[(size_t)k * 256 + c]) : (unsigned short)0;
}

// ---------------------------------------------------------------------------
// MFMA GEMM: out[M,256] = A[M,K] @ W[K,256]  (A fp32 or bf16; W as WT bf16)
// Block 256 thr = 4 waves; tile BM=64 x BN=256; wave owns 64x64 quadrant.
// A staged to LDS in fragment order [kc][row] (bf16x8); B read from WT global.
// ---------------------------------------------------------------------------
template <int K, int KPAD, bool BIAS_RELU, bool A_BF16, bool OUT_BF16>
__global__ __launch_bounds__(256) void mfma_linear(const void* __restrict__ Av,
                                                   const unsigned short* __restrict__ WT,
                                                   const float* __restrict__ bias,
                                                   void* __restrict__ outv, int M) {
    __shared__ bf16x8 Alds[4][64];
    const int tid = threadIdx.x;
    const int wid = tid >> 6;
    const int lane = tid & 63;
    const int r0 = blockIdx.x * 64;
    const int c0 = wid * 64;
    const int l15 = lane & 15;
    const int lk = lane >> 4;
    const int srow = tid & 63;
    const int skc = tid >> 6;

    f32x4 acc[4][4];
    #pragma unroll
    for (int m = 0; m < 4; ++m)
        #pragma unroll
        for (int n = 0; n < 4; ++n)
            acc[m][n] = (f32x4)0.f;

    for (int kk = 0; kk < KPAD; kk += 32) {
        // ---- stage A chunk (fp32->bf16 convert fused) ----
        int grow = r0 + srow;
        int gk = kk + skc * 8;
        bf16x8 av;
        if (A_BF16) {
            const unsigned short* Ab = (const unsigned short*)Av;
            if (grow < M) {
                av = *(const bf16x8*)(Ab + (size_t)grow * K + gk);
            } else {
                #pragma unroll
                for (int j = 0; j < 8; ++j) av[j] = 0;
            }
        } else {
            const float* Af = (const float*)Av;
            #pragma unroll
            for (int j = 0; j < 8; ++j) {
                int k = gk + j;
                float f = (grow < M && k < K) ? Af[(size_t)grow * K + k] : 0.f;
                av[j] = (short)f2bf(f);
            }
        }
        Alds[skc][srow] = av;
        __syncthreads();

        // ---- B fragments straight from WT (L2-resident) ----
        bf16x8 bfrag[4];
        #pragma unroll
        for (int n = 0; n < 4; ++n) {
            int col = c0 + n * 16 + l15;
            bfrag[n] = *(const bf16x8*)(WT + (size_t)col * KPAD + kk + lk * 8);
        }
        bf16x8 afrag[4];
        #pragma unroll
        for (int m = 0; m < 4; ++m) afrag[m] = Alds[lk][m * 16 + l15];

        #pragma unroll
        for (int m = 0; m < 4; ++m)
            #pragma unroll
            for (int n = 0; n < 4; ++n)
                acc[m][n] = __builtin_amdgcn_mfma_f32_16x16x32_bf16(afrag[m], bfrag[n],
                                                                    acc[m][n], 0, 0, 0);
        __syncthreads();
    }

    // ---- epilogue: C/D layout col=lane&15, row=(lane>>4)*4+j (verified) ----
    #pragma unroll
    for (int n = 0; n < 4; ++n) {
        int c = c0 + n * 16 + l15;
        float b = BIAS_RELU ? bias[c] : 0.f;
        #pragma unroll
        for (int m = 0; m < 4; ++m) {
            int rbase = r0 + m * 16 + lk * 4;
            #pragma unroll
            for (int j = 0; j < 4; ++j) {
                int r = rbase + j;
                if (r < M) {
                    float v = acc[m][n][j];
                    if (BIAS_RELU) v = fmaxf(v + b, 0.f);
                    if (OUT_BF16)
                        ((unsigned short*)outv)[(size_t)r * 256 + c] = f2bf(v);
                    else
                        ((float*)outv)[(size_t)r * 256 + c] = v;
                }
            }
        }
    }
}

// ---------------------------------------------------------------------------
// el/er: per-node per-head dot of h (bf16) with attn vectors. Wave per node.
// ---------------------------------------------------------------------------
__global__ __launch_bounds__(256) void eler_kernel(const unsigned short* __restrict__ h,
                                                   const float* __restrict__ al,
                                                   const float* __restrict__ ar,
                                                   float* __restrict__ el,
                                                   float* __restrict__ er, int N) {
    int wid = threadIdx.x >> 6, lane = threadIdx.x & 63;
    int n = blockIdx.x * 4 + wid;
    if (n >= N) return;
    ushort4 hv = *(const ushort4*)(h + (size_t)n * 256 + lane * 4);
    float4 av = ((const float4*)al)[lane];
    float4 rv = ((const float4*)ar)[lane];
    float h0 = bf2f(hv.x), h1 = bf2f(hv.y), h2 = bf2f(hv.z), h3 = bf2f(hv.w);
    float pl = h0 * av.x + h1 * av.y + h2 * av.z + h3 * av.w;
    float pr = h0 * rv.x + h1 * rv.y + h2 * rv.z + h3 * rv.w;
    #pragma unroll
    for (int off = 1; off < 16; off <<= 1) {
        pl += __shfl_xor(pl, off, 64);
        pr += __shfl_xor(pr, off, 64);
    }
    if ((lane & 15) == 0) {
        int hh = lane >> 4;
        el[n * 4 + hh] = pl;
        er[n * 4 + hh] = pr;
    }
}

// ---------------------------------------------------------------------------
// per-edge exp(leaky_relu(el[src]+er[dst])) and segment-sum into s[dst]
// ---------------------------------------------------------------------------
__global__ void ex_kernel(const int* __restrict__ src, const int* __restrict__ dst,
                          const float* __restrict__ el, const float* __restrict__ er,
                          float* __restrict__ ex, float* __restrict__ s, int E4) {
    int i = blockIdx.x * blockDim.x + threadIdx.x;
    if (i >= E4) return;
    int e = i >> 2, h = i & 3;
    int sn = src[e], dn = dst[e];
    float v = el[sn * 4 + h] + er[dn * 4 + h];
    v = (v > 0.f) ? v : NEG_SLOPE * v;
    float xv = expf(v);
    ex[i] = xv;
    atomicAdd(&s[dn * 4 + h], xv);
}

// ---------------------------------------------------------------------------
// Aggregation: wave per dst node, lane owns 4 channels (bf16x4 gather of h).
// out = (sum ex*h[src])/s + res + bias, relu.
// ---------------------------------------------------------------------------
template <bool OUT_BF16>
__global__ __launch_bounds__(256) void agg_kernel(const int* __restrict__ row_ptr,
                                                  const int2* __restrict__ csr,
                                                  const unsigned short* __restrict__ hfeat,
                                                  const float* __restrict__ ex,
                                                  const float* __restrict__ s,
                                                  const unsigned short* __restrict__ res,
                                                  const float* __restrict__ bias,
                                                  void* __restrict__ out, int N) {
    int wid = threadIdx.x >> 6, lane = threadIdx.x & 63;
    int n = blockIdx.x * 4 + wid;
    if (n >= N) return;
    int head = lane >> 4;
    int start = row_ptr[n], end = row_ptr[n + 1];
    float a0 = 0.f, a1 = 0.f, a2 = 0.f, a3 = 0.f;
    for (int p = start; p < end; ++p) {
        int2 se = csr[p];
        float w = ex[(size_t)se.y * 4 + head];
        ushort4 hv = *(const ushort4*)(hfeat + (size_t)se.x * 256 + lane * 4);
        a0 = fmaf(w, bf2f(hv.x), a0);
        a1 = fmaf(w, bf2f(hv.y), a1);
        a2 = fmaf(w, bf2f(hv.z), a2);
        a3 = fmaf(w, bf2f(hv.w), a3);
    }
    float sinv = 1.f / s[n * 4 + head];
    ushort4 rv = *(const ushort4*)(res + (size_t)n * 256 + lane * 4);
    float4 bv = ((const float4*)bias)[lane];
    float v0 = fmaxf(a0 * sinv + bf2f(rv.x) + bv.x, 0.f);
    float v1 = fmaxf(a1 * sinv + bf2f(rv.y) + bv.y, 0.f);
    float v2 = fmaxf(a2 * sinv + bf2f(rv.z) + bv.z, 0.f);
    float v3 = fmaxf(a3 * sinv + bf2f(rv.w) + bv.w, 0.f);
    if (OUT_BF16) {
        ushort4 o;
        o.x = f2bf(v0); o.y = f2bf(v1); o.z = f2bf(v2); o.w = f2bf(v3);
        *(ushort4*)((unsigned short*)out + (size_t)n * 256 + lane * 4) = o;
    } else {
        float4 o = make_float4(v0, v1, v2, v3);
        ((float4*)out)[(size_t)n * 64 + lane] = o;
    }
}

// ---------------------------------------------------------------------------
// Column-wise max pool (post-ReLU values >= 0 -> int atomicMax valid)
// ---------------------------------------------------------------------------
__global__ void maxpool_kernel(const float* __restrict__ x, float* __restrict__ pooled, int N) {
    int c = threadIdx.x;
    float m = 0.f;
    for (int n = blockIdx.x; n < N; n += gridDim.x)
        m = fmaxf(m, x[(size_t)n * 256 + c]);
    atomicMax(reinterpret_cast<int*>(pooled) + c, __float_as_int(m));
}

// ---------------------------------------------------------------------------
// Final tiny MLP: [1,256] @ [256,128] relu @ [128,2]
// ---------------------------------------------------------------------------
__global__ __launch_bounds__(128) void mlp_kernel(const float* __restrict__ pooled,
                                                  const float* __restrict__ Ws,
                                                  const float* __restrict__ bs,
                                                  const float* __restrict__ Wc,
                                                  const float* __restrict__ bc,
                                                  float* __restrict__ out) {
    __shared__ float p[256];
    __shared__ float hbuf[128];
    int t = threadIdx.x;
    p[t] = pooled[t];
    p[t + 128] = pooled[t + 128];
    __syncthreads();
    float acc = bs[t];
    for (int k = 0; k < 256; ++k) acc = fmaf(p[k], Ws[k * 128 + t], acc);
    hbuf[t] = fmaxf(acc, 0.f);
    __syncthreads();
    if (t < 2) {
        float o = bc[t];
        for (int k = 0; k < 128; ++k) o = fmaf(hbuf[k], Wc[k * 2 + t], o);
        out[t] = o;
    }
}

// ---------------------------------------------------------------------------
extern "C" void kernel_launch(void* const* d_in, const int* in_sizes, int n_in,
                              void* d_out, int out_size, void* d_ws, size_t ws_size,
                              hipStream_t stream) {
    const float* doc   = (const float*)d_in[0];
    const float* wordf = (const float*)d_in[1];
    const int*   src   = (const int*)d_in[2];
    const int*   dst   = (const int*)d_in[3];
    const float* Wd    = (const float*)d_in[4];
    const float* bd    = (const float*)d_in[5];
    const float* Ww    = (const float*)d_in[6];
    const float* bw    = (const float*)d_in[7];
    const float* W1    = (const float*)d_in[8];
    const float* al1   = (const float*)d_in[9];
    const float* ar1   = (const float*)d_in[10];
    const float* b1    = (const float*)d_in[11];
    const float* resW1 = (const float*)d_in[12];
    const float* W2    = (const float*)d_in[13];
    const float* al2   = (const float*)d_in[14];
    const float* ar2   = (const float*)d_in[15];
    const float* b2    = (const float*)d_in[16];
    const float* Wsm   = (const float*)d_in[17];
    const float* bsm   = (const float*)d_in[18];
    const float* Wc    = (const float*)d_in[19];
    const float* bc    = (const float*)d_in[20];

    const int NDOC  = in_sizes[0] / 768;
    const int NWORD = in_sizes[1] / 300;
    const int N     = NDOC + NWORD;
    const int E     = in_sizes[2];

    char* ws = (char*)d_ws;
    size_t off = 0;
    auto alloc = [&](size_t bytes) -> char* {
        char* p = ws + off;
        off = (off + bytes + 255) & ~(size_t)255;
        return p;
    };
    typedef unsigned short u16;
    u16*   Xb     = (u16*)alloc((size_t)N * 256 * 2);   // layer-1 input (bf16)
    u16*   Hb     = (u16*)alloc((size_t)N * 256 * 2);   // h features (bf16)
    u16*   Rb     = (u16*)alloc((size_t)N * 256 * 2);   // res1 (bf16)
    u16*   X2     = (u16*)alloc((size_t)N * 256 * 2);   // layer-1 out / layer-2 in (bf16)
    float* O32    = (float*)alloc((size_t)N * 256 * 4); // layer-2 out (fp32)
    float* EL     = (float*)alloc((size_t)N * 4 * 4);
    float* ER     = (float*)alloc((size_t)N * 4 * 4);
    float* S      = (float*)alloc((size_t)N * 4 * 4);
    float* EX     = (float*)alloc((size_t)E * 4 * 4);
    int*   rowptr = (int*)alloc((size_t)(N + 1) * 4);
    int*   cursor = (int*)alloc((size_t)N * 4);
    int*   deg    = (int*)alloc((size_t)N * 4);
    int2*  csr    = (int2*)alloc((size_t)E * 8);
    u16*   WTd    = (u16*)alloc((size_t)256 * 768 * 2);
    u16*   WTw    = (u16*)alloc((size_t)256 * 320 * 2);
    u16*   WT1    = (u16*)alloc((size_t)256 * 256 * 2);
    u16*   WTr    = (u16*)alloc((size_t)256 * 256 * 2);
    u16*   WT2    = (u16*)alloc((size_t)256 * 256 * 2);
    float* pooled = (float*)alloc(256 * 4);

    const int eg  = (E + 255) / 256;
    const int e4g = (E * 4 + 255) / 256;
    const int ng64 = (N + 63) / 64;

    // --- CSR build (by dst), reused for both layers ---
    hipMemsetAsync(deg, 0, (size_t)N * 4, stream);
    hist_kernel<<<eg, 256, 0, stream>>>(dst, deg, E);
    scan_kernel<<<1, 1024, 0, stream>>>(deg, rowptr, cursor, N);
    scatter_kernel<<<eg, 256, 0, stream>>>(src, dst, cursor, csr, E);

    // --- weight transposes to bf16 ---
    wt_kernel<<<(256 * 768 + 255) / 256, 256, 0, stream>>>(Wd, WTd, 768, 768);
    wt_kernel<<<(256 * 320 + 255) / 256, 256, 0, stream>>>(Ww, WTw, 300, 320);
    wt_kernel<<<(256 * 256 + 255) / 256, 256, 0, stream>>>(W1, WT1, 256, 256);
    wt_kernel<<<(256 * 256 + 255) / 256, 256, 0, stream>>>(resW1, WTr, 256, 256);
    wt_kernel<<<(256 * 256 + 255) / 256, 256, 0, stream>>>(W2, WT2, 256, 256);

    // --- input linears -> Xb (bf16) ---
    mfma_linear<768, 768, true, false, true><<<(NDOC + 63) / 64, 256, 0, stream>>>(
        doc, WTd, bd, Xb, NDOC);
    mfma_linear<300, 320, true, false, true><<<(NWORD + 63) / 64, 256, 0, stream>>>(
        wordf, WTw, bw, Xb + (size_t)NDOC * 256, NWORD);

    // --- GAT layer 1 ---
    mfma_linear<256, 256, false, true, true><<<ng64, 256, 0, stream>>>(Xb, WTr, nullptr, Rb, N);
    mfma_linear<256, 256, false, true, true><<<ng64, 256, 0, stream>>>(Xb, WT1, nullptr, Hb, N);
    eler_kernel<<<(N + 3) / 4, 256, 0, stream>>>(Hb, al1, ar1, EL, ER, N);
    hipMemsetAsync(S, 0, (size_t)N * 16, stream);
    ex_kernel<<<e4g, 256, 0, stream>>>(src, dst, EL, ER, EX, S, E * 4);
    agg_kernel<true><<<(N + 3) / 4, 256, 0, stream>>>(rowptr, csr, Hb, EX, S, Rb, b1, X2, N);

    // --- GAT layer 2 (identity residual = X2) ---
    mfma_linear<256, 256, false, true, true><<<ng64, 256, 0, stream>>>(X2, WT2, nullptr, Hb, N);
    eler_kernel<<<(N + 3) / 4, 256, 0, stream>>>(Hb, al2, ar2, EL, ER, N);
    hipMemsetAsync(S, 0, (size_t)N * 16, stream);
    ex_kernel<<<e4g, 256, 0, stream>>>(src, dst, EL, ER, EX, S, E * 4);
    agg_kernel<false><<<(N + 3) / 4, 256, 0, stream>>>(rowptr, csr, Hb, EX, S, X2, b2, O32, N);

    // --- max pool + classifier ---
    hipMemsetAsync(pooled, 0, 256 * 4, stream);
    maxpool_kernel<<<256, 256, 0, stream>>>(O32, pooled, N);
    mlp_kernel<<<1, 128, 0, stream>>>(pooled, Wsm, bsm, Wc, bc, (float*)d_out);
}

// Round 13
// 675.437 us; speedup vs baseline: 2.1170x; 1.2714x over previous
//
#include <hip/hip_runtime.h>

#define NEG_SLOPE 0.2f

typedef __attribute__((ext_vector_type(8))) short bf16x8;
typedef __attribute__((ext_vector_type(4))) float f32x4;

__device__ __forceinline__ unsigned short f2bf(float x) {
    unsigned u = __float_as_uint(x);
    unsigned r = (u + 0x7fffu + ((u >> 16) & 1u)) >> 16;
    return (unsigned short)r;
}
__device__ __forceinline__ float bf2f(unsigned short b) {
    return __uint_as_float(((unsigned)b) << 16);
}

// ---------------------------------------------------------------------------
// CSR build: histogram -> single-block scan -> scatter (src only; edge id unused)
// ---------------------------------------------------------------------------
__global__ void hist_kernel(const int* __restrict__ dst, int* __restrict__ deg, int E) {
    for (int i = blockIdx.x * blockDim.x + threadIdx.x; i < E; i += gridDim.x * blockDim.x)
        atomicAdd(&deg[dst[i]], 1);
}

__global__ __launch_bounds__(1024) void scan_kernel(const int* __restrict__ deg,
                                                    int* __restrict__ row_ptr,
                                                    int* __restrict__ cursor, int n) {
    __shared__ int wave_part[16];
    __shared__ int carry_s;
    const int tid = threadIdx.x;
    const int lane = tid & 63;
    const int wid = tid >> 6;
    if (tid == 0) carry_s = 0;
    __syncthreads();
    for (int base = 0; base < n; base += 4096) {
        int idx0 = base + tid * 4;
        int v0 = (idx0 + 0 < n) ? deg[idx0 + 0] : 0;
        int v1 = (idx0 + 1 < n) ? deg[idx0 + 1] : 0;
        int v2 = (idx0 + 2 < n) ? deg[idx0 + 2] : 0;
        int v3 = (idx0 + 3 < n) ? deg[idx0 + 3] : 0;
        int tsum = v0 + v1 + v2 + v3;
        int inc = tsum;
        #pragma unroll
        for (int off = 1; off < 64; off <<= 1) {
            int o = __shfl_up(inc, off, 64);
            if (lane >= off) inc += o;
        }
        if (lane == 63) wave_part[wid] = inc;
        __syncthreads();
        if (tid == 0) {
            int run = 0;
            #pragma unroll
            for (int w = 0; w < 16; ++w) { int t = wave_part[w]; wave_part[w] = run; run += t; }
        }
        __syncthreads();
        int run = inc - tsum + wave_part[wid] + carry_s;
        if (idx0 + 0 < n) { row_ptr[idx0 + 0] = run; cursor[idx0 + 0] = run; } run += v0;
        if (idx0 + 1 < n) { row_ptr[idx0 + 1] = run; cursor[idx0 + 1] = run; } run += v1;
        if (idx0 + 2 < n) { row_ptr[idx0 + 2] = run; cursor[idx0 + 2] = run; } run += v2;
        if (idx0 + 3 < n) { row_ptr[idx0 + 3] = run; cursor[idx0 + 3] = run; } run += v3;
        __syncthreads();
        if (tid == 1023) carry_s += wave_part[15] + inc;
        __syncthreads();
    }
    if (tid == 0) row_ptr[n] = carry_s;
}

__global__ void scatter_kernel(const int* __restrict__ src, const int* __restrict__ dst,
                               int* __restrict__ cursor, int* __restrict__ csr, int E) {
    for (int i = blockIdx.x * blockDim.x + threadIdx.x; i < E; i += gridDim.x * blockDim.x) {
        int d = dst[i];
        int pos = atomicAdd(&cursor[d], 1);
        csr[pos] = src[i];
    }
}

// ---------------------------------------------------------------------------
// All weight transposes to bf16 in one kernel. WT[c][k], k zero-padded to KPAD.
// ---------------------------------------------------------------------------
__global__ void wt_all_kernel(const float* __restrict__ Wd, const float* __restrict__ Ww,
                              const float* __restrict__ W1, const float* __restrict__ Wr,
                              const float* __restrict__ W2,
                              unsigned short* __restrict__ WTd, unsigned short* __restrict__ WTw,
                              unsigned short* __restrict__ WT1, unsigned short* __restrict__ WTr,
                              unsigned short* __restrict__ WT2) {
    const int S0 = 256 * 768, S1 = 256 * 320, S2 = 256 * 256;
    int i = blockIdx.x * 256 + threadIdx.x;
    if (i < S0) { int c = i / 768, k = i - c * 768; WTd[i] = f2bf(Wd[(size_t)k * 256 + c]); return; }
    i -= S0;
    if (i < S1) { int c = i / 320, k = i - c * 320;
                  WTw[i] = (k < 300) ? f2bf(Ww[(size_t)k * 256 + c]) : (unsigned short)0; return; }
    i -= S1;
    if (i < S2) { int c = i >> 8, k = i & 255; WT1[i] = f2bf(W1[(size_t)k * 256 + c]); return; }
    i -= S2;
    if (i < S2) { int c = i >> 8, k = i & 255; WTr[i] = f2bf(Wr[(size_t)k * 256 + c]); return; }
    i -= S2;
    if (i < S2) { int c = i >> 8, k = i & 255; WT2[i] = f2bf(W2[(size_t)k * 256 + c]); return; }
}

// ---------------------------------------------------------------------------
// MFMA GEMM: out[M,256](bf16) = A[M,K] @ W[K,256], optional bias+relu,
// optional fused el/er epilogue (el[r,h]=sum_d h*al[h,d]) from fp32 acc.
// Block 256 thr = 4 waves; BM=64 x BN=256; wave wid owns cols [wid*64,..) = head wid.
// ---------------------------------------------------------------------------
template <int K, int KPAD, bool BIAS_RELU, bool A_BF16, bool ELER>
__global__ __launch_bounds__(256) void mfma_linear(const void* __restrict__ Av,
                                                   const unsigned short* __restrict__ WT,
                                                   const float* __restrict__ bias,
                                                   unsigned short* __restrict__ outp,
                                                   const float* __restrict__ al,
                                                   const float* __restrict__ ar,
                                                   float* __restrict__ el,
                                                   float* __restrict__ er, int M) {
    __shared__ bf16x8 Alds[4][64];
    const int tid = threadIdx.x;
    const int wid = tid >> 6;
    const int lane = tid & 63;
    const int r0 = blockIdx.x * 64;
    const int c0 = wid * 64;
    const int l15 = lane & 15;
    const int lk = lane >> 4;
    const int srow = tid & 63;
    const int skc = tid >> 6;

    f32x4 acc[4][4];
    #pragma unroll
    for (int m = 0; m < 4; ++m)
        #pragma unroll
        for (int n = 0; n < 4; ++n)
            acc[m][n] = (f32x4)0.f;

    for (int kk = 0; kk < KPAD; kk += 32) {
        int grow = r0 + srow;
        int gk = kk + skc * 8;
        bf16x8 av;
        if (A_BF16) {
            const unsigned short* Ab = (const unsigned short*)Av;
            if (grow < M) {
                av = *(const bf16x8*)(Ab + (size_t)grow * K + gk);
            } else {
                #pragma unroll
                for (int j = 0; j < 8; ++j) av[j] = 0;
            }
        } else {
            const float* Af = (const float*)Av;
            #pragma unroll
            for (int j = 0; j < 8; ++j) {
                int k = gk + j;
                float f = (grow < M && k < K) ? Af[(size_t)grow * K + k] : 0.f;
                av[j] = (short)f2bf(f);
            }
        }
        Alds[skc][srow] = av;
        __syncthreads();

        bf16x8 bfrag[4];
        #pragma unroll
        for (int n = 0; n < 4; ++n) {
            int col = c0 + n * 16 + l15;
            bfrag[n] = *(const bf16x8*)(WT + (size_t)col * KPAD + kk + lk * 8);
        }
        bf16x8 afrag[4];
        #pragma unroll
        for (int m = 0; m < 4; ++m) afrag[m] = Alds[lk][m * 16 + l15];

        #pragma unroll
        for (int m = 0; m < 4; ++m)
            #pragma unroll
            for (int n = 0; n < 4; ++n)
                acc[m][n] = __builtin_amdgcn_mfma_f32_16x16x32_bf16(afrag[m], bfrag[n],
                                                                    acc[m][n], 0, 0, 0);
        __syncthreads();
    }

    // C/D layout: col = lane&15 (+n*16), row = (lane>>4)*4 + j (+m*16) [HW-verified]
    #pragma unroll
    for (int n = 0; n < 4; ++n) {
        int c = c0 + n * 16 + l15;
        float b = BIAS_RELU ? bias[c] : 0.f;
        #pragma unroll
        for (int m = 0; m < 4; ++m) {
            int rbase = r0 + m * 16 + lk * 4;
            #pragma unroll
            for (int j = 0; j < 4; ++j) {
                int r = rbase + j;
                if (r < M) {
                    float v = acc[m][n][j];
                    if (BIAS_RELU) v = fmaxf(v + b, 0.f);
                    outp[(size_t)r * 256 + c] = f2bf(v);
                }
            }
        }
    }

    if (ELER) {
        const float* alh = al + wid * 64;
        const float* arh = ar + wid * 64;
        #pragma unroll
        for (int m = 0; m < 4; ++m) {
            float pl[4] = {0.f, 0.f, 0.f, 0.f};
            float pr[4] = {0.f, 0.f, 0.f, 0.f};
            #pragma unroll
            for (int n = 0; n < 4; ++n) {
                int d = n * 16 + l15;
                float wl = alh[d], wr = arh[d];
                #pragma unroll
                for (int j = 0; j < 4; ++j) {
                    pl[j] = fmaf(acc[m][n][j], wl, pl[j]);
                    pr[j] = fmaf(acc[m][n][j], wr, pr[j]);
                }
            }
            #pragma unroll
            for (int j = 0; j < 4; ++j) {
                #pragma unroll
                for (int off = 1; off < 16; off <<= 1) {
                    pl[j] += __shfl_xor(pl[j], off, 64);
                    pr[j] += __shfl_xor(pr[j], off, 64);
                }
            }
            if (l15 == 0) {
                #pragma unroll
                for (int j = 0; j < 4; ++j) {
                    int r = r0 + m * 16 + lk * 4 + j;
                    if (r < M) {
                        el[r * 4 + wid] = pl[j];
                        er[r * 4 + wid] = pr[j];
                    }
                }
            }
        }
    }
}

// ---------------------------------------------------------------------------
// Fused attention + aggregation, single pass (softmax denominator folded):
// out = (Σ_e exp(lrelu(el[src]+er[n]))·h[src]) / (Σ_e exp(...)) + res + bias, relu
// Wave per dst node; lane owns 4 channels; edge loop unrolled x4 for MLP.
// ---------------------------------------------------------------------------
__global__ __launch_bounds__(256) void agg_fused(const int* __restrict__ row_ptr,
                                                 const int* __restrict__ csr,
                                                 const unsigned short* __restrict__ hfeat,
                                                 const float* __restrict__ el,
                                                 const float* __restrict__ er,
                                                 const unsigned short* __restrict__ res,
                                                 const float* __restrict__ bias,
                                                 unsigned short* __restrict__ out, int N) {
    int wid = threadIdx.x >> 6, lane = threadIdx.x & 63;
    int n = blockIdx.x * 4 + wid;
    if (n >= N) return;
    int head = lane >> 4;
    float ern = er[n * 4 + head];
    int start = row_ptr[n], end = row_ptr[n + 1];
    float s = 0.f, a0 = 0.f, a1 = 0.f, a2 = 0.f, a3 = 0.f;
    int p = start;
    for (; p + 4 <= end; p += 4) {
        int i0 = csr[p], i1 = csr[p + 1], i2 = csr[p + 2], i3 = csr[p + 3];
        float e0 = el[i0 * 4 + head] + ern;
        float e1 = el[i1 * 4 + head] + ern;
        float e2 = el[i2 * 4 + head] + ern;
        float e3 = el[i3 * 4 + head] + ern;
        ushort4 h0 = *(const ushort4*)(hfeat + (size_t)i0 * 256 + lane * 4);
        ushort4 h1 = *(const ushort4*)(hfeat + (size_t)i1 * 256 + lane * 4);
        ushort4 h2 = *(const ushort4*)(hfeat + (size_t)i2 * 256 + lane * 4);
        ushort4 h3 = *(const ushort4*)(hfeat + (size_t)i3 * 256 + lane * 4);
        e0 = (e0 > 0.f) ? e0 : NEG_SLOPE * e0;
        e1 = (e1 > 0.f) ? e1 : NEG_SLOPE * e1;
        e2 = (e2 > 0.f) ? e2 : NEG_SLOPE * e2;
        e3 = (e3 > 0.f) ? e3 : NEG_SLOPE * e3;
        float w0 = __expf(e0), w1 = __expf(e1), w2 = __expf(e2), w3 = __expf(e3);
        s += (w0 + w1) + (w2 + w3);
        a0 = fmaf(w0, bf2f(h0.x), a0); a1 = fmaf(w0, bf2f(h0.y), a1);
        a2 = fmaf(w0, bf2f(h0.z), a2); a3 = fmaf(w0, bf2f(h0.w), a3);
        a0 = fmaf(w1, bf2f(h1.x), a0); a1 = fmaf(w1, bf2f(h1.y), a1);
        a2 = fmaf(w1, bf2f(h1.z), a2); a3 = fmaf(w1, bf2f(h1.w), a3);
        a0 = fmaf(w2, bf2f(h2.x), a0); a1 = fmaf(w2, bf2f(h2.y), a1);
        a2 = fmaf(w2, bf2f(h2.z), a2); a3 = fmaf(w2, bf2f(h2.w), a3);
        a0 = fmaf(w3, bf2f(h3.x), a0); a1 = fmaf(w3, bf2f(h3.y), a1);
        a2 = fmaf(w3, bf2f(h3.z), a2); a3 = fmaf(w3, bf2f(h3.w), a3);
    }
    for (; p < end; ++p) {
        int i0 = csr[p];
        float e0 = el[i0 * 4 + head] + ern;
        ushort4 h0 = *(const ushort4*)(hfeat + (size_t)i0 * 256 + lane * 4);
        e0 = (e0 > 0.f) ? e0 : NEG_SLOPE * e0;
        float w0 = __expf(e0);
        s += w0;
        a0 = fmaf(w0, bf2f(h0.x), a0); a1 = fmaf(w0, bf2f(h0.y), a1);
        a2 = fmaf(w0, bf2f(h0.z), a2); a3 = fmaf(w0, bf2f(h0.w), a3);
    }
    float sinv = 1.f / s;
    ushort4 rv = *(const ushort4*)(res + (size_t)n * 256 + lane * 4);
    float4 bv = ((const float4*)bias)[lane];
    ushort4 o;
    o.x = f2bf(fmaxf(a0 * sinv + bf2f(rv.x) + bv.x, 0.f));
    o.y = f2bf(fmaxf(a1 * sinv + bf2f(rv.y) + bv.y, 0.f));
    o.z = f2bf(fmaxf(a2 * sinv + bf2f(rv.z) + bv.z, 0.f));
    o.w = f2bf(fmaxf(a3 * sinv + bf2f(rv.w) + bv.w, 0.f));
    *(ushort4*)(out + (size_t)n * 256 + lane * 4) = o;
}

// ---------------------------------------------------------------------------
// Column-wise max pool over bf16 input (post-ReLU >= 0 -> int atomicMax valid)
// ---------------------------------------------------------------------------
__global__ void maxpool_kernel(const unsigned short* __restrict__ x,
                               float* __restrict__ pooled, int N) {
    int c = threadIdx.x;
    float m = 0.f;
    for (int n = blockIdx.x; n < N; n += gridDim.x)
        m = fmaxf(m, bf2f(x[(size_t)n * 256 + c]));
    atomicMax(reinterpret_cast<int*>(pooled) + c, __float_as_int(m));
}

// ---------------------------------------------------------------------------
// Final tiny MLP: [1,256] @ [256,128] relu @ [128,2]
// ---------------------------------------------------------------------------
__global__ __launch_bounds__(128) void mlp_kernel(const float* __restrict__ pooled,
                                                  const float* __restrict__ Ws,
                                                  const float* __restrict__ bs,
                                                  const float* __restrict__ Wc,
                                                  const float* __restrict__ bc,
                                                  float* __restrict__ out) {
    __shared__ float p[256];
    __shared__ float hbuf[128];
    int t = threadIdx.x;
    p[t] = pooled[t];
    p[t + 128] = pooled[t + 128];
    __syncthreads();
    float acc = bs[t];
    for (int k = 0; k < 256; ++k) acc = fmaf(p[k], Ws[k * 128 + t], acc);
    hbuf[t] = fmaxf(acc, 0.f);
    __syncthreads();
    if (t < 2) {
        float o = bc[t];
        for (int k = 0; k < 128; ++k) o = fmaf(hbuf[k], Wc[k * 2 + t], o);
        out[t] = o;
    }
}

// ---------------------------------------------------------------------------
extern "C" void kernel_launch(void* const* d_in, const int* in_sizes, int n_in,
                              void* d_out, int out_size, void* d_ws, size_t ws_size,
                              hipStream_t stream) {
    const float* doc   = (const float*)d_in[0];
    const float* wordf = (const float*)d_in[1];
    const int*   src   = (const int*)d_in[2];
    const int*   dst   = (const int*)d_in[3];
    const float* Wd    = (const float*)d_in[4];
    const float* bd    = (const float*)d_in[5];
    const float* Ww    = (const float*)d_in[6];
    const float* bw    = (const float*)d_in[7];
    const float* W1    = (const float*)d_in[8];
    const float* al1   = (const float*)d_in[9];
    const float* ar1   = (const float*)d_in[10];
    const float* b1    = (const float*)d_in[11];
    const float* resW1 = (const float*)d_in[12];
    const float* W2    = (const float*)d_in[13];
    const float* al2   = (const float*)d_in[14];
    const float* ar2   = (const float*)d_in[15];
    const float* b2    = (const float*)d_in[16];
    const float* Wsm   = (const float*)d_in[17];
    const float* bsm   = (const float*)d_in[18];
    const float* Wc    = (const float*)d_in[19];
    const float* bc    = (const float*)d_in[20];

    const int NDOC  = in_sizes[0] / 768;
    const int NWORD = in_sizes[1] / 300;
    const int N     = NDOC + NWORD;
    const int E     = in_sizes[2];

    char* ws = (char*)d_ws;
    size_t off = 0;
    auto alloc = [&](size_t bytes) -> char* {
        char* p = ws + off;
        off = (off + bytes + 255) & ~(size_t)255;
        return p;
    };
    typedef unsigned short u16;
    u16*   Xb     = (u16*)alloc((size_t)N * 256 * 2);   // layer-1 input (bf16)
    u16*   Hb     = (u16*)alloc((size_t)N * 256 * 2);   // h features (bf16)
    u16*   Rb     = (u16*)alloc((size_t)N * 256 * 2);   // res1 (bf16)
    u16*   X2     = (u16*)alloc((size_t)N * 256 * 2);   // layer-1 out / layer-2 in (bf16)
    u16*   O2     = (u16*)alloc((size_t)N * 256 * 2);   // layer-2 out (bf16)
    float* EL     = (float*)alloc((size_t)N * 4 * 4);
    float* ER     = (float*)alloc((size_t)N * 4 * 4);
    int*   rowptr = (int*)alloc((size_t)(N + 1) * 4);
    int*   cursor = (int*)alloc((size_t)N * 4);
    int*   deg    = (int*)alloc((size_t)N * 4);
    int*   csr    = (int*)alloc((size_t)E * 4);
    u16*   WTd    = (u16*)alloc((size_t)256 * 768 * 2);
    u16*   WTw    = (u16*)alloc((size_t)256 * 320 * 2);
    u16*   WT1    = (u16*)alloc((size_t)256 * 256 * 2);
    u16*   WTr    = (u16*)alloc((size_t)256 * 256 * 2);
    u16*   WT2    = (u16*)alloc((size_t)256 * 256 * 2);
    float* pooled = (float*)alloc(256 * 4);

    const int eg   = (E + 255) / 256;
    const int ng64 = (N + 63) / 64;
    const int ngagg = (N + 3) / 4;
    const int WT_TOTAL = 256 * 768 + 256 * 320 + 3 * 256 * 256;

    // --- CSR build (by dst), reused for both layers ---
    hipMemsetAsync(deg, 0, (size_t)N * 4, stream);
    hist_kernel<<<eg, 256, 0, stream>>>(dst, deg, E);
    scan_kernel<<<1, 1024, 0, stream>>>(deg, rowptr, cursor, N);
    scatter_kernel<<<eg, 256, 0, stream>>>(src, dst, cursor, csr, E);

    // --- all weight transposes in one dispatch ---
    wt_all_kernel<<<(WT_TOTAL + 255) / 256, 256, 0, stream>>>(Wd, Ww, W1, resW1, W2,
                                                              WTd, WTw, WT1, WTr, WT2);

    // --- input linears -> Xb (bf16) ---
    mfma_linear<768, 768, true, false, false><<<(NDOC + 63) / 64, 256, 0, stream>>>(
        doc, WTd, bd, Xb, nullptr, nullptr, nullptr, nullptr, NDOC);
    mfma_linear<300, 320, true, false, false><<<(NWORD + 63) / 64, 256, 0, stream>>>(
        wordf, WTw, bw, Xb + (size_t)NDOC * 256, nullptr, nullptr, nullptr, nullptr, NWORD);

    // --- GAT layer 1 ---
    mfma_linear<256, 256, false, true, false><<<ng64, 256, 0, stream>>>(
        Xb, WTr, nullptr, Rb, nullptr, nullptr, nullptr, nullptr, N);
    mfma_linear<256, 256, false, true, true><<<ng64, 256, 0, stream>>>(
        Xb, WT1, nullptr, Hb, al1, ar1, EL, ER, N);
    agg_fused<<<ngagg, 256, 0, stream>>>(rowptr, csr, Hb, EL, ER, Rb, b1, X2, N);

    // --- GAT layer 2 (identity residual = X2) ---
    mfma_linear<256, 256, false, true, true><<<ng64, 256, 0, stream>>>(
        X2, WT2, nullptr, Hb, al2, ar2, EL, ER, N);
    agg_fused<<<ngagg, 256, 0, stream>>>(rowptr, csr, Hb, EL, ER, X2, b2, O2, N);

    // --- max pool + classifier ---
    hipMemsetAsync(pooled, 0, 256 * 4, stream);
    maxpool_kernel<<<256, 256, 0, stream>>>(O2, pooled, N);
    mlp_kernel<<<1, 128, 0, stream>>>(pooled, Wsm, bsm, Wc, bc, (float*)d_out);
}